// Round 1
// baseline (400.580 us; speedup 1.0000x reference)
//
#include <hip/hip_runtime.h>
#include <hip/hip_bf16.h>

typedef unsigned short u16;
typedef __attribute__((ext_vector_type(8))) short bf16x8;
typedef __attribute__((ext_vector_type(16))) float f32x16;
typedef __attribute__((ext_vector_type(4))) int int4v;

#define CIN 128
#define COUT 128
#define HWSZ 4096
#define RC 16
#define EPS 1e-5f

// ---------------- Kernel 1: attention logits ----------------
__global__ __launch_bounds__(256) void k_logits(const float* __restrict__ x,
                                                const float* __restrict__ mask_w,
                                                const float* __restrict__ mask_b,
                                                float* __restrict__ attn) {
    int b = blockIdx.y;
    int s = blockIdx.x * 256 + threadIdx.x;
    const float* xb = x + ((size_t)b * CIN) * HWSZ + s;
    float acc = 0.f;
#pragma unroll 8
    for (int c = 0; c < CIN; ++c) acc = fmaf(xb[(size_t)c * HWSZ], mask_w[c], acc);
    attn[b * HWSZ + s] = acc + mask_b[0];
}

// ---------------- Kernel 2: softmax over 4096 (in place) ----------------
__global__ __launch_bounds__(256) void k_softmax(float* __restrict__ attn) {
    int b = blockIdx.x, t = threadIdx.x;
    float* row = attn + b * HWSZ;
    float v[16];
    float m = -1e30f;
#pragma unroll
    for (int i = 0; i < 16; ++i) { v[i] = row[t + i * 256]; m = fmaxf(m, v[i]); }
    __shared__ float red[256];
    red[t] = m;
    __syncthreads();
    for (int off = 128; off > 0; off >>= 1) {
        if (t < off) red[t] = fmaxf(red[t], red[t + off]);
        __syncthreads();
    }
    m = red[0];
    __syncthreads();
    float s = 0.f;
#pragma unroll
    for (int i = 0; i < 16; ++i) { v[i] = __expf(v[i] - m); s += v[i]; }
    red[t] = s;
    __syncthreads();
    for (int off = 128; off > 0; off >>= 1) {
        if (t < off) red[t] += red[t + off];
        __syncthreads();
    }
    float inv = 1.f / red[0];
#pragma unroll
    for (int i = 0; i < 16; ++i) row[t + i * 256] = v[i] * inv;
}

// ---------------- Kernel 3: context = x . attn ----------------
__global__ __launch_bounds__(256) void k_context(const float* __restrict__ x,
                                                 const float* __restrict__ attn,
                                                 float* __restrict__ ctx) {
    int bc = blockIdx.x;             // b*128 + c
    int b = bc >> 7, t = threadIdx.x;
    const float* xr = x + (size_t)bc * HWSZ;
    const float* ar = attn + b * HWSZ;
    float s = 0.f;
#pragma unroll
    for (int i = 0; i < 16; ++i) s = fmaf(xr[t + i * 256], ar[t + i * 256], s);
    __shared__ float red[256];
    red[t] = s;
    __syncthreads();
    for (int off = 128; off > 0; off >>= 1) {
        if (t < off) red[t] += red[t + off];
        __syncthreads();
    }
    if (t == 0) ctx[bc] = red[0];
}

// ---------------- Kernel 4: transform + per-sample weight generation ----------------
// Writes wgen[b][kh][kw][co][ci] (bf16), XOR-swizzled within each 32KB plane:
//   plane_byte = (co<<8) + (ci<<1), stored at plane_byte ^ ((co&7)<<4)
__global__ __launch_bounds__(256) void k_genw(const float* __restrict__ ctx,
                                              const float* __restrict__ t1_w,
                                              const float* __restrict__ t1_b,
                                              const float* __restrict__ ln_g,
                                              const float* __restrict__ ln_b,
                                              const float* __restrict__ t2_w,
                                              const float* __restrict__ t2_b,
                                              const float* __restrict__ fc_w,
                                              const float* __restrict__ fc_b,
                                              u16* __restrict__ wgen) {
    int b = blockIdx.x, t = threadIdx.x;
    __shared__ float c_sh[CIN];
    __shared__ float t_sh[RC];
    __shared__ float s_sh[256];
    if (t < CIN) c_sh[t] = ctx[b * CIN + t];
    __syncthreads();
    if (t < RC) {
        float a = 0.f;
        for (int c = 0; c < CIN; ++c) a = fmaf(c_sh[c], t1_w[t * CIN + c], a);
        t_sh[t] = a + t1_b[t];
    }
    __syncthreads();
    // LayerNorm over 16 (computed redundantly per thread), ReLU, then gate o = t
    float tv[RC], mu = 0.f;
#pragma unroll
    for (int r = 0; r < RC; ++r) { tv[r] = t_sh[r]; mu += tv[r]; }
    mu *= (1.f / RC);
    float var = 0.f;
#pragma unroll
    for (int r = 0; r < RC; ++r) { float d = tv[r] - mu; var = fmaf(d, d, var); }
    var *= (1.f / RC);
    float rs = rsqrtf(var + EPS);
    float aa[RC];
#pragma unroll
    for (int r = 0; r < RC; ++r)
        aa[r] = fmaxf(0.f, fmaf((tv[r] - mu) * rs, ln_g[r], ln_b[r]));
    {
        float xw = 0.f;
#pragma unroll
        for (int r = 0; r < RC; ++r) xw = fmaf(aa[r], t2_w[t * RC + r], xw);
        xw += t2_b[t];
        s_sh[t] = 1.f / (1.f + __expf(-xw));
    }
    __syncthreads();
    // weight generation: w[co][ci][kh][kw] = fc_w[flat]*gate[2*co + (ci>=64)] + fc_b[flat]
    u16* wb = wgen + (size_t)b * 9 * 16384;
    for (int p = 0; p < 9; ++p) {
        u16* wp = wb + p * 16384;
        for (int i = t; i < 16384; i += 256) {
            int co = i >> 7, ci = i & 127;
            int flat = co * 1152 + ci * 9 + p;
            float val = fmaf(fc_w[flat], s_sh[2 * co + (ci >> 6)], fc_b[flat]);
            int byte = ((co << 8) | (ci << 1)) ^ ((co & 7) << 4);
            __hip_bfloat16 hv = __float2bfloat16(val);
            wp[byte >> 1] = *reinterpret_cast<u16*>(&hv);
        }
    }
}

// ---------------- Kernel 5: per-sample 3x3 conv via implicit GEMM (MFMA bf16) ----------------
// block = (b, y-pair). Tile: M=128 (co) x N=128 (2 rows x 64 x), K = 9 x 128 (ci).
__global__ __launch_bounds__(256, 2) void k_conv(const float* __restrict__ x,
                                                 const u16* __restrict__ wgen,
                                                 float* __restrict__ out) {
    __shared__ __align__(16) u16 At[16384];      // 128co x 128ci bf16, swizzled
    __shared__ __align__(16) u16 Bt[132 * 128];  // 132 rows (2 y-rows x 66 halo-x) x 128ci, swizzled

    int bid = blockIdx.x;
    int b = bid >> 5, yp = bid & 31, y0 = yp * 2;
    int t = threadIdx.x;
    int lane = t & 63, w = t >> 6;
    int wr = w >> 1, wc = w & 1;
    int l31 = lane & 31, l5 = lane >> 5;

    const float* xb = x + (size_t)b * CIN * HWSZ;
    const u16* wbase = wgen + (size_t)b * 9 * 16384;

    f32x16 acc00 = {0}, acc01 = {0}, acc10 = {0}, acc11 = {0};

    for (int kh = 0; kh < 3; ++kh) {
        __syncthreads();  // prior compute done before overwriting Bt (and At)
        // ---- stage Bt: Xp rows y0+r+kh-1, xh in [0,66) -> x-src = xh-1, bf16, transposed+swizzled
        for (int idx = t; idx < 2 * 128 * 66; idx += 256) {
            int xh = idx % 66;
            int rest = idx / 66;
            int ci = rest & 127, r = rest >> 7;
            int y = y0 + r + kh - 1;
            int xs = xh - 1;
            float v = 0.f;
            if ((unsigned)y < 64u && (unsigned)xs < 64u) v = xb[((size_t)ci * 64 + y) * 64 + xs];
            int rowb = r * 66 + xh;
            int byte = ((rowb << 8) | (ci << 1)) ^ ((rowb & 7) << 4);
            __hip_bfloat16 hv = __float2bfloat16(v);
            Bt[byte >> 1] = *reinterpret_cast<u16*>(&hv);
        }
        for (int kw = 0; kw < 3; ++kw) {
            if (kw) __syncthreads();  // prior kw compute done before At overwrite
            // ---- stage At: 32KB linear copy (source is pre-swizzled)
            {
                const int4v* src = (const int4v*)(wbase + (kh * 3 + kw) * 16384);
                int4v* dst = (int4v*)At;
#pragma unroll
                for (int i = 0; i < 8; ++i) dst[t + i * 256] = src[t + i * 256];
            }
            __syncthreads();  // staging visible
            // ---- GEMM over ci=128 in K-chunks of 16
            int rowA0 = wr * 64 + l31;
            int rowA1 = rowA0 + 32;
            int rowB0 = wc * 66 + l31 + kw;
            int rowB1 = rowB0 + 32;
            int sA0 = (rowA0 & 7) << 4, sA1 = (rowA1 & 7) << 4;
            int sB0 = (rowB0 & 7) << 4, sB1 = (rowB1 & 7) << 4;
            const char* Ab = (const char*)At;
            const char* Bb = (const char*)Bt;
#pragma unroll
            for (int ks = 0; ks < 8; ++ks) {
                int kb = ks * 32 + l5 * 16;
                bf16x8 a0 = *(const bf16x8*)(Ab + (((rowA0 << 8) | kb) ^ sA0));
                bf16x8 a1 = *(const bf16x8*)(Ab + (((rowA1 << 8) | kb) ^ sA1));
                bf16x8 b0 = *(const bf16x8*)(Bb + (((rowB0 << 8) | kb) ^ sB0));
                bf16x8 b1 = *(const bf16x8*)(Bb + (((rowB1 << 8) | kb) ^ sB1));
                acc00 = __builtin_amdgcn_mfma_f32_32x32x16_bf16(a0, b0, acc00, 0, 0, 0);
                acc01 = __builtin_amdgcn_mfma_f32_32x32x16_bf16(a0, b1, acc01, 0, 0, 0);
                acc10 = __builtin_amdgcn_mfma_f32_32x32x16_bf16(a1, b0, acc10, 0, 0, 0);
                acc11 = __builtin_amdgcn_mfma_f32_32x32x16_bf16(a1, b1, acc11, 0, 0, 0);
            }
        }
    }

    // ---- writeout: C/D layout col=lane&31, row=(reg&3)+8*(reg>>2)+4*(lane>>5)
    float* ob = out + (size_t)b * COUT * HWSZ;
    int y = y0 + wc;
    auto store_acc = [&](const f32x16& v, int m2, int n4) {
        float* colp = ob + (size_t)(wr * 64 + m2 * 32) * HWSZ + y * 64 + n4 * 32 + l31;
#pragma unroll
        for (int r = 0; r < 16; ++r) {
            int row32 = (r & 3) + ((r >> 2) << 3) + (l5 << 2);
            colp[(size_t)row32 * HWSZ] = v[r];
        }
    };
    store_acc(acc00, 0, 0);
    store_acc(acc01, 0, 1);
    store_acc(acc10, 1, 0);
    store_acc(acc11, 1, 1);
}

extern "C" void kernel_launch(void* const* d_in, const int* in_sizes, int n_in,
                              void* d_out, int out_size, void* d_ws, size_t ws_size,
                              hipStream_t stream) {
    const float* x      = (const float*)d_in[0];
    const float* mask_w = (const float*)d_in[1];
    const float* mask_b = (const float*)d_in[2];
    const float* t1_w   = (const float*)d_in[3];
    const float* t1_b   = (const float*)d_in[4];
    const float* ln_g   = (const float*)d_in[5];
    const float* ln_b   = (const float*)d_in[6];
    const float* t2_w   = (const float*)d_in[7];
    const float* t2_b   = (const float*)d_in[8];
    const float* fc_w   = (const float*)d_in[9];
    const float* fc_b   = (const float*)d_in[10];
    float* out = (float*)d_out;

    char* ws = (char*)d_ws;
    float* attn = (float*)ws;                      // 32*4096*4   = 524288 B
    float* ctx  = (float*)(ws + 524288);           // 32*128*4    = 16384 B
    u16*   wgen = (u16*)(ws + 540672);             // 32*9*16384*2 = 9437184 B

    k_logits <<<dim3(16, 32), 256, 0, stream>>>(x, mask_w, mask_b, attn);
    k_softmax<<<32,           256, 0, stream>>>(attn);
    k_context<<<4096,         256, 0, stream>>>(x, attn, ctx);
    k_genw   <<<32,           256, 0, stream>>>(ctx, t1_w, t1_b, ln_g, ln_b,
                                                t2_w, t2_b, fc_w, fc_b, wgen);
    k_conv   <<<1024,         256, 0, stream>>>(x, wgen, out);
}

// Round 2
// 200.754 us; speedup vs baseline: 1.9954x; 1.9954x over previous
//
#include <hip/hip_runtime.h>
#include <hip/hip_bf16.h>

typedef unsigned short u16;
typedef unsigned int u32;
typedef __attribute__((ext_vector_type(8))) short bf16x8;
typedef __attribute__((ext_vector_type(16))) float f32x16;
typedef __attribute__((ext_vector_type(4))) int int4v;
typedef __attribute__((ext_vector_type(4))) float f32x4;

#define CIN 128
#define COUT 128
#define HWSZ 4096
#define RC 16
#define EPS 1e-5f

__device__ __forceinline__ float b2f(u16 u) {
    u32 v = ((u32)u) << 16;
    union { u32 i; float f; } c; c.i = v; return c.f;
}

__device__ __forceinline__ void dma16(const void* g, void* l) {
    __builtin_amdgcn_global_load_lds((const __attribute__((address_space(1))) void*)g,
                                     (__attribute__((address_space(3))) void*)l, 16, 0, 0);
}

// ---------------- Kernel 1: transpose x -> xT bf16 (pre-swizzled) + logits ----------------
// xT row g = b*4096 + y*64 + xs holds 128 ci bf16 (256B); 16B chunk c stored at c ^ (xs&7).
__global__ __launch_bounds__(256) void k_xform(const float* __restrict__ x,
                                               const float* __restrict__ mask_w,
                                               const float* __restrict__ mask_b,
                                               u16* __restrict__ xT,
                                               float* __restrict__ attn) {
    int y = blockIdx.x, b = blockIdx.y, t = threadIdx.x;
    __shared__ float tile[128 * 65];   // stride 65 floats: conflict-light both ways
    __shared__ float red[256];

    int c4 = t & 15, ci0 = t >> 4;     // 16 lanes cover one 256B ci-row
#pragma unroll
    for (int i = 0; i < 8; ++i) {
        int ci = ci0 + i * 16;
        f32x4 v = *(const f32x4*)(x + (size_t)(b * 128 + ci) * 4096 + y * 64 + c4 * 4);
        float* tr = tile + ci * 65 + c4 * 4;
        tr[0] = v.x; tr[1] = v.y; tr[2] = v.z; tr[3] = v.w;
    }
    __syncthreads();

    // logits partials (4 groups of 32 ci per pixel)
    {
        int xs = t & 63, grp = t >> 6;
        float a = 0.f;
#pragma unroll 8
        for (int ci = grp * 32; ci < grp * 32 + 32; ++ci)
            a = fmaf(tile[ci * 65 + xs], mask_w[ci], a);
        red[grp * 64 + xs] = a;
    }

    // bf16 pack + swizzled write: thread -> (xs = t>>2, chunk quad q = t&3)
    {
        int xs = t >> 2, q = t & 3;
        u16* dst = xT + ((size_t)b * 4096 + y * 64 + xs) * 128;
        int sw = xs & 7;
#pragma unroll
        for (int k = 0; k < 4; ++k) {
            int cd = q * 4 + k;          // data chunk: ci in [8cd, 8cd+8)
            int cs = cd ^ sw;            // stored slot
            u16 tmp[8];
#pragma unroll
            for (int e = 0; e < 8; ++e) {
                __hip_bfloat16 h = __float2bfloat16(tile[(cd * 8 + e) * 65 + xs]);
                tmp[e] = *reinterpret_cast<u16*>(&h);
            }
            *(int4v*)(dst + cs * 8) = *(int4v*)tmp;
        }
    }
    __syncthreads();
    if (t < 64)
        attn[b * HWSZ + y * 64 + t] =
            red[t] + red[64 + t] + red[128 + t] + red[192 + t] + mask_b[0];
}

// ---------------- Kernel 2: softmax over 4096 (in place) + zero ctx ----------------
__global__ __launch_bounds__(256) void k_softmax(float* __restrict__ attn,
                                                 float* __restrict__ ctx) {
    int b = blockIdx.x, t = threadIdx.x;
    if (t < 128) ctx[b * 128 + t] = 0.f;
    float* row = attn + b * HWSZ;
    float v[16];
    float m = -1e30f;
#pragma unroll
    for (int i = 0; i < 16; ++i) { v[i] = row[t + i * 256]; m = fmaxf(m, v[i]); }
    __shared__ float red[256];
    red[t] = m;
    __syncthreads();
    for (int off = 128; off > 0; off >>= 1) {
        if (t < off) red[t] = fmaxf(red[t], red[t + off]);
        __syncthreads();
    }
    m = red[0];
    __syncthreads();
    float s = 0.f;
#pragma unroll
    for (int i = 0; i < 16; ++i) { v[i] = __expf(v[i] - m); s += v[i]; }
    red[t] = s;
    __syncthreads();
    for (int off = 128; off > 0; off >>= 1) {
        if (t < off) red[t] += red[t + off];
        __syncthreads();
    }
    float inv = 1.f / red[0];
#pragma unroll
    for (int i = 0; i < 16; ++i) row[t + i * 256] = v[i] * inv;
}

// ---------------- Kernel 3: context = xT . attn (atomic partials) ----------------
__global__ __launch_bounds__(256) void k_context(const u16* __restrict__ xT,
                                                 const float* __restrict__ attn,
                                                 float* __restrict__ ctx) {
    int bid = blockIdx.x;
    int b = bid >> 4, sc = bid & 15;
    int t = threadIdx.x, w = t >> 6, l = t & 63;
    const char* xb = (const char*)(xT + (size_t)b * HWSZ * 128);
    float a0 = 0.f, a1 = 0.f;
    int s0 = sc * 256 + w * 64;
    for (int j = 0; j < 64; ++j) {
        int s = s0 + j;
        float av = attn[b * HWSZ + s];
        u32 p = *(const u32*)(xb + (size_t)s * 256 + ((l << 2) ^ ((s & 7) << 4)));
        a0 = fmaf(av, b2f((u16)(p & 0xffff)), a0);
        a1 = fmaf(av, b2f((u16)(p >> 16)), a1);
    }
    __shared__ float red[4][128];
    red[w][2 * l] = a0;
    red[w][2 * l + 1] = a1;
    __syncthreads();
    if (t < 128)
        atomicAdd(&ctx[b * 128 + t], red[0][t] + red[1][t] + red[2][t] + red[3][t]);
}

// ---------------- Kernel 4: transform -> sigmoid gates [b][256] ----------------
__global__ __launch_bounds__(256) void k_transform(const float* __restrict__ ctx,
                                                   const float* __restrict__ t1_w,
                                                   const float* __restrict__ t1_b,
                                                   const float* __restrict__ ln_g,
                                                   const float* __restrict__ ln_b,
                                                   const float* __restrict__ t2_w,
                                                   const float* __restrict__ t2_b,
                                                   float* __restrict__ gates) {
    int b = blockIdx.x, t = threadIdx.x;
    __shared__ float c_sh[CIN];
    __shared__ float t_sh[RC];
    if (t < CIN) c_sh[t] = ctx[b * CIN + t];
    __syncthreads();
    if (t < RC) {
        float a = 0.f;
        for (int c = 0; c < CIN; ++c) a = fmaf(c_sh[c], t1_w[t * CIN + c], a);
        t_sh[t] = a + t1_b[t];
    }
    __syncthreads();
    float tv[RC], mu = 0.f;
#pragma unroll
    for (int r = 0; r < RC; ++r) { tv[r] = t_sh[r]; mu += tv[r]; }
    mu *= (1.f / RC);
    float var = 0.f;
#pragma unroll
    for (int r = 0; r < RC; ++r) { float d = tv[r] - mu; var = fmaf(d, d, var); }
    var *= (1.f / RC);
    float rs = rsqrtf(var + EPS);
    float xw = 0.f;
#pragma unroll
    for (int r = 0; r < RC; ++r) {
        float a = fmaxf(0.f, fmaf((tv[r] - mu) * rs, ln_g[r], ln_b[r]));
        xw = fmaf(a, t2_w[t * RC + r], xw);
    }
    xw += t2_b[t];
    gates[b * 256 + t] = 1.f / (1.f + __expf(-xw));
}

// ---------------- Kernel 5: weight generation (pre-swizzled planes) ----------------
// wgen[b][p][co][ci] bf16; 16B chunk c of row co stored at c ^ (co&7).
__global__ __launch_bounds__(256) void k_genw(const float* __restrict__ fc_w,
                                              const float* __restrict__ fc_b,
                                              const float* __restrict__ gates,
                                              u16* __restrict__ wgen) {
    int bid = blockIdx.x;
    int b = bid >> 6, c = bid & 63;
    int t = threadIdx.x;
    int i = c * 256 + t;
    int co = i >> 7, ci = i & 127;
    float gate = gates[b * 256 + 2 * co + (ci >> 6)];
    int flat = co * 1152 + ci * 9;
    int elem = (((co << 8) | (ci << 1)) ^ ((co & 7) << 4)) >> 1;
    u16* wb = wgen + (size_t)b * 9 * 16384;
#pragma unroll
    for (int p = 0; p < 9; ++p) {
        float v = fmaf(fc_w[flat + p], gate, fc_b[flat + p]);
        __hip_bfloat16 h = __float2bfloat16(v);
        wb[p * 16384 + elem] = *reinterpret_cast<u16*>(&h);
    }
}

// ---------------- Kernel 6: per-sample 3x3 conv, all staging via global_load_lds ----------------
__global__ __launch_bounds__(256, 2) void k_conv(const u16* __restrict__ xT,
                                                 const u16* __restrict__ wgen,
                                                 float* __restrict__ out) {
    __shared__ __align__(16) u16 At[16384];       // 128co x 128ci, swizzled by co&7
    __shared__ __align__(16) u16 Bt[132 * 128];   // rows r*66+xh, verbatim xT rows (swizzled by xs&7)

    int bid0 = blockIdx.x;
    // XCD swizzle: 4 consecutive samples per XCD
    int xcd = bid0 & 7, i5 = bid0 >> 3;
    int b = xcd * 4 + (i5 >> 5);
    int yp = i5 & 31, y0 = yp * 2;

    int t = threadIdx.x;
    int lane = t & 63, w = t >> 6;
    int wr = w >> 1, wc = w & 1;
    int l31 = lane & 31, l5 = lane >> 5;

    const char* xb = (const char*)(xT + (size_t)b * HWSZ * 128);
    const char* wbase = (const char*)(wgen + (size_t)b * 9 * 16384);

    f32x16 acc00 = {0}, acc01 = {0}, acc10 = {0}, acc11 = {0};

    for (int kh = 0; kh < 3; ++kh) {
        __syncthreads();  // previous reads of At/Bt done
        // ---- stage Bt via DMA: per r, interior rows 1..64 = one 16KB linear run
        for (int r = 0; r < 2; ++r) {
            int y = y0 + r + kh - 1;
            char* base = (char*)Bt + (r * 66) * 256;
            if ((unsigned)y < 64u) {
                const char* src = xb + (size_t)y * 64 * 256;
#pragma unroll
                for (int i = 0; i < 4; ++i) {
                    int off = (w * 4 + i) * 1024;
                    dma16(src + off + lane * 16, base + 256 + off);
                }
                if (t < 32) {  // halo rows xh=0 and xh=65 -> zeros
                    int hr = (t >> 4) * 65;
                    *(int4v*)(base + hr * 256 + (t & 15) * 16) = int4v{0, 0, 0, 0};
                }
            } else {
                for (int i = t; i < 1056; i += 256)
                    *(int4v*)(base + i * 16) = int4v{0, 0, 0, 0};
            }
        }
        for (int kw = 0; kw < 3; ++kw) {
            if (kw) __syncthreads();  // previous At reads done
            {
                const char* src = wbase + (kh * 3 + kw) * 32768;
                char* dstb = (char*)At;
#pragma unroll
                for (int i = 0; i < 8; ++i) {
                    int off = (w * 8 + i) * 1024;
                    dma16(src + off + lane * 16, dstb + off);
                }
            }
            __syncthreads();  // drains vmcnt (DMA complete) + lgkm
            // ---- GEMM over ci=128
            int rowA0 = wr * 64 + l31, rowA1 = rowA0 + 32;
            int rowB0 = wc * 66 + l31 + kw, rowB1 = rowB0 + 32;
            int sA0 = (rowA0 & 7) << 4, sA1 = (rowA1 & 7) << 4;
            int sB = ((l31 + kw - 1) & 7) << 4;  // xs-parity swizzle; same for rowB0/rowB1
            const char* Ab = (const char*)At;
            const char* Bb = (const char*)Bt;
#pragma unroll
            for (int ks = 0; ks < 8; ++ks) {
                int kb = ks * 32 + l5 * 16;
                bf16x8 a0 = *(const bf16x8*)(Ab + ((rowA0 << 8) | (kb ^ sA0)));
                bf16x8 a1 = *(const bf16x8*)(Ab + ((rowA1 << 8) | (kb ^ sA1)));
                bf16x8 b0 = *(const bf16x8*)(Bb + ((rowB0 << 8) | (kb ^ sB)));
                bf16x8 b1 = *(const bf16x8*)(Bb + ((rowB1 << 8) | (kb ^ sB)));
                acc00 = __builtin_amdgcn_mfma_f32_32x32x16_bf16(a0, b0, acc00, 0, 0, 0);
                acc01 = __builtin_amdgcn_mfma_f32_32x32x16_bf16(a0, b1, acc01, 0, 0, 0);
                acc10 = __builtin_amdgcn_mfma_f32_32x32x16_bf16(a1, b0, acc10, 0, 0, 0);
                acc11 = __builtin_amdgcn_mfma_f32_32x32x16_bf16(a1, b1, acc11, 0, 0, 0);
            }
        }
    }

    // ---- writeout: C/D layout col=lane&31, row=(reg&3)+8*(reg>>2)+4*(lane>>5)
    float* ob = out + (size_t)b * COUT * HWSZ;
    int y = y0 + wc;
    auto store_acc = [&](const f32x16& v, int m2, int n4) {
        float* colp = ob + (size_t)(wr * 64 + m2 * 32) * HWSZ + y * 64 + n4 * 32 + l31;
#pragma unroll
        for (int r = 0; r < 16; ++r) {
            int row32 = (r & 3) + ((r >> 2) << 3) + (l5 << 2);
            colp[(size_t)row32 * HWSZ] = v[r];
        }
    };
    store_acc(acc00, 0, 0);
    store_acc(acc01, 0, 1);
    store_acc(acc10, 1, 0);
    store_acc(acc11, 1, 1);
}

extern "C" void kernel_launch(void* const* d_in, const int* in_sizes, int n_in,
                              void* d_out, int out_size, void* d_ws, size_t ws_size,
                              hipStream_t stream) {
    const float* x      = (const float*)d_in[0];
    const float* mask_w = (const float*)d_in[1];
    const float* mask_b = (const float*)d_in[2];
    const float* t1_w   = (const float*)d_in[3];
    const float* t1_b   = (const float*)d_in[4];
    const float* ln_g   = (const float*)d_in[5];
    const float* ln_b   = (const float*)d_in[6];
    const float* t2_w   = (const float*)d_in[7];
    const float* t2_b   = (const float*)d_in[8];
    const float* fc_w   = (const float*)d_in[9];
    const float* fc_b   = (const float*)d_in[10];
    float* out = (float*)d_out;

    char* ws = (char*)d_ws;
    u16*   xT    = (u16*)ws;                         // 33,554,432 B
    float* attn  = (float*)(ws + 33554432);          // 524,288 B
    float* ctx   = (float*)(ws + 34078720);          // 16,384 B
    float* gates = (float*)(ws + 34095104);          // 32,768 B
    u16*   wgen  = (u16*)(ws + 34127872);            // 9,437,184 B  (total ~41.6 MB)

    k_xform    <<<dim3(64, 32), 256, 0, stream>>>(x, mask_w, mask_b, xT, attn);
    k_softmax  <<<32,  256, 0, stream>>>(attn, ctx);
    k_context  <<<512, 256, 0, stream>>>(xT, attn, ctx);
    k_transform<<<32,  256, 0, stream>>>(ctx, t1_w, t1_b, ln_g, ln_b, t2_w, t2_b, gates);
    k_genw     <<<2048, 256, 0, stream>>>(fc_w, fc_b, gates, wgen);
    k_conv     <<<1024, 256, 0, stream>>>(xT, wgen, out);
}